// Round 3
// baseline (342.140 us; speedup 1.0000x reference)
//
#include <hip/hip_runtime.h>
#include <math.h>

#define NB 64
#define NT 2048
#define NH 512
#define NOUT 128
#define TCH 32          // t-chunks (blocks per batch) for flash pass
#define TPC 64          // timesteps per chunk (NT/TCH)
#define RPW 16          // rows per wave (TPC / 4 waves)

// ---------------------------------------------------------------------------
// K1: v[b,h] = sum_k W_score[h,k] * h_t[b,k]   (h_t = hidden[b, T-1, :])
// grid (NB, 4): block computes 128 h-values for one batch.
// ---------------------------------------------------------------------------
__global__ __launch_bounds__(128) void k_v(const float* __restrict__ hidden,
                                           const float* __restrict__ Wscore,
                                           float* __restrict__ v) {
    __shared__ float ht[NH];
    const int b = blockIdx.x;
    const float* hrow = hidden + ((size_t)b * NT + (NT - 1)) * NH;
    for (int k = threadIdx.x; k < NH; k += 128) ht[k] = hrow[k];
    __syncthreads();
    const int h = blockIdx.y * 128 + threadIdx.x;
    const float4* wr = reinterpret_cast<const float4*>(Wscore + (size_t)h * NH);
    float acc = 0.f;
#pragma unroll 8
    for (int k4 = 0; k4 < NH / 4; ++k4) {
        float4 w = wr[k4];
        acc += w.x * ht[k4 * 4 + 0] + w.y * ht[k4 * 4 + 1] +
               w.z * ht[k4 * 4 + 2] + w.w * ht[k4 * 4 + 3];
    }
    v[(size_t)b * NH + h] = acc;
}

// ---------------------------------------------------------------------------
// K2 (fused flash + finisher): one pass over hidden; per (b,chunk) block
// computes chunk-partial online-softmax context. The LAST finishing block of
// each batch (device-scope atomic counter) combines all chunks, concats h_t,
// does the W_out GEMV + tanh, and writes the batch's output row.
// ---------------------------------------------------------------------------
__global__ __launch_bounds__(256) void k_fused(const float* __restrict__ hidden,
                                               const float* __restrict__ v,
                                               const float* __restrict__ Wout,
                                               float* __restrict__ out,
                                               float* __restrict__ pctx,
                                               float* __restrict__ pm,
                                               float* __restrict__ pl,
                                               int* __restrict__ cnt) {
    const int b = blockIdx.x / TCH;
    const int tc = blockIdx.x % TCH;
    const int wid = threadIdx.x >> 6;
    const int lane = threadIdx.x & 63;

    const float4* vb = reinterpret_cast<const float4*>(v + (size_t)b * NH);
    const float4 v0 = vb[lane];
    const float4 v1 = vb[64 + lane];

    const float4* hbase = reinterpret_cast<const float4*>(
        hidden + ((size_t)b * NT + tc * TPC + wid * RPW) * NH);

    float4 c0 = {0.f, 0.f, 0.f, 0.f}, c1 = {0.f, 0.f, 0.f, 0.f};
    float m = -INFINITY, l = 0.f;

#pragma unroll 8
    for (int r = 0; r < RPW; ++r) {
        float4 h0 = hbase[(size_t)r * 128 + lane];
        float4 h1 = hbase[(size_t)r * 128 + 64 + lane];
        float s = h0.x * v0.x + h0.y * v0.y + h0.z * v0.z + h0.w * v0.w +
                  h1.x * v1.x + h1.y * v1.y + h1.z * v1.z + h1.w * v1.w;
#pragma unroll
        for (int off = 32; off >= 1; off >>= 1) s += __shfl_xor(s, off, 64);
        // wave-uniform online softmax update
        if (s > m) {
            float sc = __expf(m - s);
            c0.x *= sc; c0.y *= sc; c0.z *= sc; c0.w *= sc;
            c1.x *= sc; c1.y *= sc; c1.z *= sc; c1.w *= sc;
            l *= sc;
            m = s;
        }
        float p = __expf(s - m);
        l += p;
        c0.x += p * h0.x; c0.y += p * h0.y; c0.z += p * h0.z; c0.w += p * h0.w;
        c1.x += p * h1.x; c1.y += p * h1.y; c1.z += p * h1.z; c1.w += p * h1.w;
    }

    // cross-wave combine (cl reused by the finisher afterwards)
    __shared__ float cl[4][NH];
    __shared__ float ml[4], ll[4];
    __shared__ int isLast;
    reinterpret_cast<float4*>(cl[wid])[lane] = c0;
    reinterpret_cast<float4*>(cl[wid])[64 + lane] = c1;
    if (lane == 0) { ml[wid] = m; ll[wid] = l; }
    __syncthreads();

    const float mb = fmaxf(fmaxf(ml[0], ml[1]), fmaxf(ml[2], ml[3]));
    const float e0 = __expf(ml[0] - mb), e1 = __expf(ml[1] - mb);
    const float e2 = __expf(ml[2] - mb), e3 = __expf(ml[3] - mb);

    const int h2 = threadIdx.x;  // float2 column, 0..255
    float2 a;
    a.x = cl[0][2 * h2] * e0 + cl[1][2 * h2] * e1 +
          cl[2][2 * h2] * e2 + cl[3][2 * h2] * e3;
    a.y = cl[0][2 * h2 + 1] * e0 + cl[1][2 * h2 + 1] * e1 +
          cl[2][2 * h2 + 1] * e2 + cl[3][2 * h2 + 1] * e3;
    reinterpret_cast<float2*>(pctx + ((size_t)b * TCH + tc) * NH)[h2] = a;
    if (threadIdx.x == 0) {
        pm[b * TCH + tc] = mb;
        pl[b * TCH + tc] = ll[0] * e0 + ll[1] * e1 + ll[2] * e2 + ll[3] * e3;
    }

    // ---- last-block-per-batch finisher ----
    __threadfence();  // make this block's pctx/pm/pl device-visible
    __syncthreads();  // all threads done with cl[] reads; pm/pl stored
    if (threadIdx.x == 0) {
        int old = atomicAdd(&cnt[b], 1);
        isLast = (old == TCH - 1);
    }
    __syncthreads();
    if (!isLast) return;
    __threadfence();  // acquire: see all other blocks' released writes

    float* pre = &cl[0][0];   // 1024 floats (cl[0], cl[1])
    float* red = &cl[2][0];   // 256 floats

    // global max / denom across chunks (small, L2-resident)
    float Mb = -INFINITY;
#pragma unroll
    for (int t = 0; t < TCH; ++t) Mb = fmaxf(Mb, pm[b * TCH + t]);
    float Lb = 0.f;
#pragma unroll
    for (int t = 0; t < TCH; ++t) Lb += pl[b * TCH + t] * __expf(pm[b * TCH + t] - Mb);
    const float invL = 1.f / Lb;

    float2 acc2 = {0.f, 0.f};
    for (int t = 0; t < TCH; ++t) {
        float e = __expf(pm[b * TCH + t] - Mb);
        float2 p = reinterpret_cast<const float2*>(pctx + ((size_t)b * TCH + t) * NH)[h2];
        acc2.x += e * p.x;
        acc2.y += e * p.y;
    }
    pre[2 * h2] = acc2.x * invL;
    pre[2 * h2 + 1] = acc2.y * invL;

    const float* hrow = hidden + ((size_t)b * NT + (NT - 1)) * NH;
    float2 hh = reinterpret_cast<const float2*>(hrow)[h2];
    pre[NH + 2 * h2] = hh.x;
    pre[NH + 2 * h2 + 1] = hh.y;
    __syncthreads();

    // GEMV: 128 outputs, 2 threads per output (split j), 2 accumulators
    const int o = threadIdx.x & 127;
    const int half = threadIdx.x >> 7;
    const int j0 = half * NH;
    float a0 = 0.f, a1 = 0.f;
#pragma unroll 8
    for (int j = j0; j < j0 + NH; j += 2) {
        a0 += pre[j] * Wout[(size_t)j * NOUT + o];
        a1 += pre[j + 1] * Wout[(size_t)(j + 1) * NOUT + o];
    }
    red[threadIdx.x] = a0 + a1;
    __syncthreads();
    if (half == 0) out[(size_t)b * NOUT + o] = tanhf(red[o] + red[128 + o]);
}

// ---------------------------------------------------------------------------
extern "C" void kernel_launch(void* const* d_in, const int* in_sizes, int n_in,
                              void* d_out, int out_size, void* d_ws, size_t ws_size,
                              hipStream_t stream) {
    const float* hidden = (const float*)d_in[0];  // (B,T,H)
    const float* Wscore = (const float*)d_in[1];  // (H,H)
    const float* Wout = (const float*)d_in[2];    // (2H,OUT)
    float* out = (float*)d_out;                   // (B,OUT) fp32

    float* ws = (float*)d_ws;
    float* v = ws;                               // NB*NH
    float* pctx = v + NB * NH;                   // NB*TCH*NH
    float* pm = pctx + (size_t)NB * TCH * NH;    // NB*TCH
    float* pl = pm + NB * TCH;                   // NB*TCH
    int* cnt = (int*)(pl + NB * TCH);            // NB

    hipMemsetAsync(cnt, 0, NB * sizeof(int), stream);
    k_v<<<dim3(NB, 4), 128, 0, stream>>>(hidden, Wscore, v);
    k_fused<<<NB * TCH, 256, 0, stream>>>(hidden, v, Wout, out, pctx, pm, pl, cnt);
}

// Round 4
// 69.372 us; speedup vs baseline: 4.9320x; 4.9320x over previous
//
#include <hip/hip_runtime.h>
#include <math.h>

#define NB 64
#define NT 2048
#define NH 512
#define NOUT 128
#define TCH 32          // t-chunks (blocks per batch) for flash pass
#define TPC 64          // timesteps per chunk (NT/TCH)
#define RPW 16          // rows per wave (TPC / 4 waves)

// ---------------------------------------------------------------------------
// K1: v[b,h] = sum_k W_score[h,k] * h_t[b,k]   (h_t = hidden[b, T-1, :])
// grid (NB, 4), 256 threads: 128 h-values per block, k split 2-way.
// ---------------------------------------------------------------------------
__global__ __launch_bounds__(256) void k_v(const float* __restrict__ hidden,
                                           const float* __restrict__ Wscore,
                                           float* __restrict__ v) {
    __shared__ float ht[NH];
    __shared__ float red[128];
    const int b = blockIdx.x;
    const float* hrow = hidden + ((size_t)b * NT + (NT - 1)) * NH;
    for (int k = threadIdx.x; k < NH; k += 256) ht[k] = hrow[k];
    __syncthreads();
    const int h = blockIdx.y * 128 + (threadIdx.x & 127);
    const int half = threadIdx.x >> 7;  // 0/1: k-slice
    const float4* wr =
        reinterpret_cast<const float4*>(Wscore + (size_t)h * NH) + half * 64;
    const float* hts = ht + half * 256;
    float acc = 0.f;
#pragma unroll 16
    for (int k4 = 0; k4 < 64; ++k4) {
        float4 w = wr[k4];
        acc += w.x * hts[k4 * 4 + 0] + w.y * hts[k4 * 4 + 1] +
               w.z * hts[k4 * 4 + 2] + w.w * hts[k4 * 4 + 3];
    }
    if (half) red[threadIdx.x & 127] = acc;
    __syncthreads();
    if (!half) v[(size_t)b * NH + h] = acc + red[threadIdx.x];
}

// ---------------------------------------------------------------------------
// K2 (flash): one pass over hidden. Per (b, chunk): each wave owns 16 rows;
// per row, read the 512-float row ONCE, use it for the score dot AND the
// online-softmax-weighted context accumulation. Cross-wave combine in LDS.
// Outputs per chunk: pctx[b,tc,0:H] (unnormalized, at max mb), pm, pl.
// ---------------------------------------------------------------------------
__global__ __launch_bounds__(256, 8) void k_flash(const float* __restrict__ hidden,
                                                  const float* __restrict__ v,
                                                  float* __restrict__ pctx,
                                                  float* __restrict__ pm,
                                                  float* __restrict__ pl) {
    const int b = blockIdx.x / TCH;
    const int tc = blockIdx.x % TCH;
    const int wid = threadIdx.x >> 6;
    const int lane = threadIdx.x & 63;

    const float4* vb = reinterpret_cast<const float4*>(v + (size_t)b * NH);
    const float4 v0 = vb[lane];
    const float4 v1 = vb[64 + lane];

    const float4* hbase = reinterpret_cast<const float4*>(
        hidden + ((size_t)b * NT + tc * TPC + wid * RPW) * NH);

    float4 c0 = {0.f, 0.f, 0.f, 0.f}, c1 = {0.f, 0.f, 0.f, 0.f};
    float m = -INFINITY, l = 0.f;

#pragma unroll 8
    for (int r = 0; r < RPW; ++r) {
        float4 h0 = hbase[(size_t)r * 128 + lane];
        float4 h1 = hbase[(size_t)r * 128 + 64 + lane];
        float s = h0.x * v0.x + h0.y * v0.y + h0.z * v0.z + h0.w * v0.w +
                  h1.x * v1.x + h1.y * v1.y + h1.z * v1.z + h1.w * v1.w;
#pragma unroll
        for (int off = 32; off >= 1; off >>= 1) s += __shfl_xor(s, off, 64);
        // wave-uniform online softmax update
        if (s > m) {
            float sc = __expf(m - s);
            c0.x *= sc; c0.y *= sc; c0.z *= sc; c0.w *= sc;
            c1.x *= sc; c1.y *= sc; c1.z *= sc; c1.w *= sc;
            l *= sc;
            m = s;
        }
        float p = __expf(s - m);
        l += p;
        c0.x += p * h0.x; c0.y += p * h0.y; c0.z += p * h0.z; c0.w += p * h0.w;
        c1.x += p * h1.x; c1.y += p * h1.y; c1.z += p * h1.z; c1.w += p * h1.w;
    }

    // cross-wave combine
    __shared__ float cl[4][NH];
    __shared__ float ml[4], ll[4];
    reinterpret_cast<float4*>(cl[wid])[lane] = c0;
    reinterpret_cast<float4*>(cl[wid])[64 + lane] = c1;
    if (lane == 0) { ml[wid] = m; ll[wid] = l; }
    __syncthreads();

    const float mb = fmaxf(fmaxf(ml[0], ml[1]), fmaxf(ml[2], ml[3]));
    const float e0 = __expf(ml[0] - mb), e1 = __expf(ml[1] - mb);
    const float e2 = __expf(ml[2] - mb), e3 = __expf(ml[3] - mb);

    const int h2 = threadIdx.x;  // float2 column, 0..255
    float2 a;
    a.x = cl[0][2 * h2] * e0 + cl[1][2 * h2] * e1 +
          cl[2][2 * h2] * e2 + cl[3][2 * h2] * e3;
    a.y = cl[0][2 * h2 + 1] * e0 + cl[1][2 * h2 + 1] * e1 +
          cl[2][2 * h2 + 1] * e2 + cl[3][2 * h2 + 1] * e3;
    reinterpret_cast<float2*>(pctx + ((size_t)b * TCH + tc) * NH)[h2] = a;
    if (threadIdx.x == 0) {
        pm[b * TCH + tc] = mb;
        pl[b * TCH + tc] = ll[0] * e0 + ll[1] * e1 + ll[2] * e2 + ll[3] * e3;
    }
}

// ---------------------------------------------------------------------------
// K3: combine chunk partials -> context, concat h_t, GEMV W_out, tanh.
// grid (NB, 2): each block does 64 of the 128 outputs, j-range split 4-way.
// ---------------------------------------------------------------------------
__global__ __launch_bounds__(256) void k_out(const float* __restrict__ hidden,
                                             const float* __restrict__ pctx,
                                             const float* __restrict__ pm,
                                             const float* __restrict__ pl,
                                             const float* __restrict__ Wout,
                                             float* __restrict__ out) {
    __shared__ float pre[2 * NH];
    __shared__ float red[4][64];
    const int b = blockIdx.x;

    // global max / denom across chunks (redundant per thread; L2-resident)
    float Mb = -INFINITY;
#pragma unroll
    for (int t = 0; t < TCH; ++t) Mb = fmaxf(Mb, pm[b * TCH + t]);
    float Lb = 0.f;
#pragma unroll
    for (int t = 0; t < TCH; ++t)
        Lb += pl[b * TCH + t] * __expf(pm[b * TCH + t] - Mb);
    const float invL = 1.f / Lb;

    // combine context; thread owns one float2 column
    const int h2 = threadIdx.x;
    float2 a = {0.f, 0.f};
#pragma unroll 4
    for (int t = 0; t < TCH; ++t) {
        float e = __expf(pm[b * TCH + t] - Mb);
        float2 p =
            reinterpret_cast<const float2*>(pctx + ((size_t)b * TCH + t) * NH)[h2];
        a.x += e * p.x;
        a.y += e * p.y;
    }
    pre[2 * h2] = a.x * invL;
    pre[2 * h2 + 1] = a.y * invL;

    const float* hrow = hidden + ((size_t)b * NT + (NT - 1)) * NH;
    float2 hh = reinterpret_cast<const float2*>(hrow)[h2];
    pre[NH + 2 * h2] = hh.x;
    pre[NH + 2 * h2 + 1] = hh.y;
    __syncthreads();

    // GEMV: this block's 64 outputs; 4 threads per output split the j-range
    const int o = blockIdx.y * 64 + (threadIdx.x & 63);
    const int js = threadIdx.x >> 6;  // 0..3
    const int j0 = js * 256;
    float a0 = 0.f, a1 = 0.f;
#pragma unroll 8
    for (int j = j0; j < j0 + 256; j += 2) {
        a0 += pre[j] * Wout[(size_t)j * NOUT + o];
        a1 += pre[j + 1] * Wout[(size_t)(j + 1) * NOUT + o];
    }
    red[js][threadIdx.x & 63] = a0 + a1;
    __syncthreads();
    if (threadIdx.x < 64) {
        int oo = blockIdx.y * 64 + threadIdx.x;
        out[(size_t)b * NOUT + oo] =
            tanhf(red[0][threadIdx.x] + red[1][threadIdx.x] +
                  red[2][threadIdx.x] + red[3][threadIdx.x]);
    }
}

// ---------------------------------------------------------------------------
extern "C" void kernel_launch(void* const* d_in, const int* in_sizes, int n_in,
                              void* d_out, int out_size, void* d_ws, size_t ws_size,
                              hipStream_t stream) {
    const float* hidden = (const float*)d_in[0];  // (B,T,H)
    const float* Wscore = (const float*)d_in[1];  // (H,H)
    const float* Wout = (const float*)d_in[2];    // (2H,OUT)
    float* out = (float*)d_out;                   // (B,OUT) fp32

    float* ws = (float*)d_ws;
    float* v = ws;                               // NB*NH
    float* pctx = v + NB * NH;                   // NB*TCH*NH
    float* pm = pctx + (size_t)NB * TCH * NH;    // NB*TCH
    float* pl = pm + NB * TCH;                   // NB*TCH

    k_v<<<dim3(NB, 4), 256, 0, stream>>>(hidden, Wscore, v);
    k_flash<<<NB * TCH, 256, 0, stream>>>(hidden, v, pctx, pm, pl);
    k_out<<<dim3(NB, 2), 256, 0, stream>>>(hidden, pctx, pm, pl, Wout, out);
}

// Round 5
// 64.512 us; speedup vs baseline: 5.3035x; 1.0753x over previous
//
#include <hip/hip_runtime.h>
#include <math.h>

#define NB 64
#define NT 2048
#define NH 512
#define NOUT 128
#define TCH 32          // t-chunks (blocks per batch) for flash pass
#define TPC 64          // timesteps per chunk (NT/TCH)
#define RPW 16          // rows per wave (TPC / 4 waves)

// ---------------------------------------------------------------------------
// K1: v[b,h] = sum_k W_score[h,k] * h_t[b,k]   (h_t = hidden[b, T-1, :])
// grid (NB, 4), 256 threads: 128 h-values per block, k split 2-way.
// ---------------------------------------------------------------------------
__global__ __launch_bounds__(256) void k_v(const float* __restrict__ hidden,
                                           const float* __restrict__ Wscore,
                                           float* __restrict__ v) {
    __shared__ float ht[NH];
    __shared__ float red[128];
    const int b = blockIdx.x;
    const float* hrow = hidden + ((size_t)b * NT + (NT - 1)) * NH;
    for (int k = threadIdx.x; k < NH; k += 256) ht[k] = hrow[k];
    __syncthreads();
    const int h = blockIdx.y * 128 + (threadIdx.x & 127);
    const int half = threadIdx.x >> 7;  // 0/1: k-slice
    const float4* wr =
        reinterpret_cast<const float4*>(Wscore + (size_t)h * NH) + half * 64;
    const float* hts = ht + half * 256;
    float acc = 0.f;
#pragma unroll 16
    for (int k4 = 0; k4 < 64; ++k4) {
        float4 w = wr[k4];
        acc += w.x * hts[k4 * 4 + 0] + w.y * hts[k4 * 4 + 1] +
               w.z * hts[k4 * 4 + 2] + w.w * hts[k4 * 4 + 3];
    }
    if (half) red[threadIdx.x & 127] = acc;
    __syncthreads();
    if (!half) v[(size_t)b * NH + h] = acc + red[threadIdx.x];
}

// ---------------------------------------------------------------------------
// K2 (flash): one pass over hidden. Per (b, chunk): each wave owns 16 rows;
// per row, read the 512-float row ONCE, use it for the score dot AND the
// online-softmax-weighted context accumulation. Register double-buffer:
// row r+1's two float4 loads are issued before row r is consumed, keeping
// 2 rows in flight per wave (+8 VGPR, stays under the 64-VGPR cliff).
// ---------------------------------------------------------------------------
__global__ __launch_bounds__(256, 8) void k_flash(const float* __restrict__ hidden,
                                                  const float* __restrict__ v,
                                                  float* __restrict__ pctx,
                                                  float* __restrict__ pm,
                                                  float* __restrict__ pl) {
    const int b = blockIdx.x / TCH;
    const int tc = blockIdx.x % TCH;
    const int wid = threadIdx.x >> 6;
    const int lane = threadIdx.x & 63;

    const float4* vb = reinterpret_cast<const float4*>(v + (size_t)b * NH);
    const float4 v0 = vb[lane];
    const float4 v1 = vb[64 + lane];

    const float4* hbase = reinterpret_cast<const float4*>(
        hidden + ((size_t)b * NT + tc * TPC + wid * RPW) * NH);

    float4 c0 = {0.f, 0.f, 0.f, 0.f}, c1 = {0.f, 0.f, 0.f, 0.f};
    float m = -INFINITY, l = 0.f;

    // prefetch row 0
    float4 a0 = hbase[lane];
    float4 a1 = hbase[64 + lane];

#pragma unroll
    for (int r = 0; r < RPW; ++r) {
        float4 h0 = a0, h1 = a1;
        if (r + 1 < RPW) {  // issue next row's loads before consuming current
            a0 = hbase[(size_t)(r + 1) * 128 + lane];
            a1 = hbase[(size_t)(r + 1) * 128 + 64 + lane];
        }
        float s = h0.x * v0.x + h0.y * v0.y + h0.z * v0.z + h0.w * v0.w +
                  h1.x * v1.x + h1.y * v1.y + h1.z * v1.z + h1.w * v1.w;
#pragma unroll
        for (int off = 32; off >= 1; off >>= 1) s += __shfl_xor(s, off, 64);
        // wave-uniform online softmax update
        if (s > m) {
            float sc = __expf(m - s);
            c0.x *= sc; c0.y *= sc; c0.z *= sc; c0.w *= sc;
            c1.x *= sc; c1.y *= sc; c1.z *= sc; c1.w *= sc;
            l *= sc;
            m = s;
        }
        float p = __expf(s - m);
        l += p;
        c0.x += p * h0.x; c0.y += p * h0.y; c0.z += p * h0.z; c0.w += p * h0.w;
        c1.x += p * h1.x; c1.y += p * h1.y; c1.z += p * h1.z; c1.w += p * h1.w;
    }

    // cross-wave combine
    __shared__ float cl[4][NH];
    __shared__ float ml[4], ll[4];
    reinterpret_cast<float4*>(cl[wid])[lane] = c0;
    reinterpret_cast<float4*>(cl[wid])[64 + lane] = c1;
    if (lane == 0) { ml[wid] = m; ll[wid] = l; }
    __syncthreads();

    const float mb = fmaxf(fmaxf(ml[0], ml[1]), fmaxf(ml[2], ml[3]));
    const float e0 = __expf(ml[0] - mb), e1 = __expf(ml[1] - mb);
    const float e2 = __expf(ml[2] - mb), e3 = __expf(ml[3] - mb);

    const int h2 = threadIdx.x;  // float2 column, 0..255
    float2 a;
    a.x = cl[0][2 * h2] * e0 + cl[1][2 * h2] * e1 +
          cl[2][2 * h2] * e2 + cl[3][2 * h2] * e3;
    a.y = cl[0][2 * h2 + 1] * e0 + cl[1][2 * h2 + 1] * e1 +
          cl[2][2 * h2 + 1] * e2 + cl[3][2 * h2 + 1] * e3;
    reinterpret_cast<float2*>(pctx + ((size_t)b * TCH + tc) * NH)[h2] = a;
    if (threadIdx.x == 0) {
        pm[b * TCH + tc] = mb;
        pl[b * TCH + tc] = ll[0] * e0 + ll[1] * e1 + ll[2] * e2 + ll[3] * e3;
    }
}

// ---------------------------------------------------------------------------
// K3: combine chunk partials -> context, concat h_t, GEMV W_out, tanh.
// grid (NB, 2): each block does 64 of the 128 outputs, j-range split 4-way.
// ---------------------------------------------------------------------------
__global__ __launch_bounds__(256) void k_out(const float* __restrict__ hidden,
                                             const float* __restrict__ pctx,
                                             const float* __restrict__ pm,
                                             const float* __restrict__ pl,
                                             const float* __restrict__ Wout,
                                             float* __restrict__ out) {
    __shared__ float pre[2 * NH];
    __shared__ float red[4][64];
    const int b = blockIdx.x;

    // global max / denom across chunks (redundant per thread; L2-resident)
    float Mb = -INFINITY;
#pragma unroll
    for (int t = 0; t < TCH; ++t) Mb = fmaxf(Mb, pm[b * TCH + t]);
    float Lb = 0.f;
#pragma unroll
    for (int t = 0; t < TCH; ++t)
        Lb += pl[b * TCH + t] * __expf(pm[b * TCH + t] - Mb);
    const float invL = 1.f / Lb;

    // combine context; thread owns one float2 column
    const int h2 = threadIdx.x;
    float2 a = {0.f, 0.f};
#pragma unroll 4
    for (int t = 0; t < TCH; ++t) {
        float e = __expf(pm[b * TCH + t] - Mb);
        float2 p =
            reinterpret_cast<const float2*>(pctx + ((size_t)b * TCH + t) * NH)[h2];
        a.x += e * p.x;
        a.y += e * p.y;
    }
    pre[2 * h2] = a.x * invL;
    pre[2 * h2 + 1] = a.y * invL;

    const float* hrow = hidden + ((size_t)b * NT + (NT - 1)) * NH;
    float2 hh = reinterpret_cast<const float2*>(hrow)[h2];
    pre[NH + 2 * h2] = hh.x;
    pre[NH + 2 * h2 + 1] = hh.y;
    __syncthreads();

    // GEMV: this block's 64 outputs; 4 threads per output split the j-range
    const int o = blockIdx.y * 64 + (threadIdx.x & 63);
    const int js = threadIdx.x >> 6;  // 0..3
    const int j0 = js * 256;
    float a0 = 0.f, a1 = 0.f;
#pragma unroll 8
    for (int j = j0; j < j0 + 256; j += 2) {
        a0 += pre[j] * Wout[(size_t)j * NOUT + o];
        a1 += pre[j + 1] * Wout[(size_t)(j + 1) * NOUT + o];
    }
    red[js][threadIdx.x & 63] = a0 + a1;
    __syncthreads();
    if (threadIdx.x < 64) {
        int oo = blockIdx.y * 64 + threadIdx.x;
        out[(size_t)b * NOUT + oo] =
            tanhf(red[0][threadIdx.x] + red[1][threadIdx.x] +
                  red[2][threadIdx.x] + red[3][threadIdx.x]);
    }
}

// ---------------------------------------------------------------------------
extern "C" void kernel_launch(void* const* d_in, const int* in_sizes, int n_in,
                              void* d_out, int out_size, void* d_ws, size_t ws_size,
                              hipStream_t stream) {
    const float* hidden = (const float*)d_in[0];  // (B,T,H)
    const float* Wscore = (const float*)d_in[1];  // (H,H)
    const float* Wout = (const float*)d_in[2];    // (2H,OUT)
    float* out = (float*)d_out;                   // (B,OUT) fp32

    float* ws = (float*)d_ws;
    float* v = ws;                               // NB*NH
    float* pctx = v + NB * NH;                   // NB*TCH*NH
    float* pm = pctx + (size_t)NB * TCH * NH;    // NB*TCH
    float* pl = pm + NB * TCH;                   // NB*TCH

    k_v<<<dim3(NB, 4), 256, 0, stream>>>(hidden, Wscore, v);
    k_flash<<<NB * TCH, 256, 0, stream>>>(hidden, v, pctx, pm, pl);
    k_out<<<dim3(NB, 2), 256, 0, stream>>>(hidden, pctx, pm, pl, Wout, out);
}